// Round 1
// baseline (221.482 us; speedup 1.0000x reference)
//
#include <hip/hip_runtime.h>
#include <math.h>

#define EPS_F 1e-7f

constexpr int Bc = 32, Tc = 8192, Kc = 16;
constexpr int ROWS   = Bc * Tc;              // 262144
constexpr int NITEMS = ROWS * Kc;            // 4194304
constexpr int BLOCK  = 256;
constexpr int NBLK   = 2048;
constexpr int ITERS  = NITEMS / (BLOCK * NBLK);  // 8
constexpr int STRIDE = BLOCK * NBLK;             // 524288

// Kernel 1: per-item loss terms + per-block partial sums.
// Layout: item tid -> row = tid>>4, k = tid&15. Lane k-position == lane&15
// (stride 524288 is a multiple of 16), so the 16 oracle slots of a row live
// in the lane's 16-lane subgroup -> matching via shuffles, zero extra traffic.
__global__ __launch_bounds__(BLOCK) void loss_main(
    const float* __restrict__ trig,    // trigger_hazard (B,T,K)
    const float* __restrict__ valp,    // validity       (B,T,K)
    const float* __restrict__ clog,    // cancel_logits  (B,T,K,3)
    const float* __restrict__ wscore,  // write_score    (B,T,1)
    const int*   __restrict__ live,    // live_mask      (B,T,K) 0/1
    const int*   __restrict__ cid,     // contract_id    (B,T,K)
    const float* __restrict__ ofire,   // oracle_fire    (B,T,K)
    const int*   __restrict__ ocan,    // oracle_cancel  (B,T,K)
    const float* __restrict__ ovalid,  // oracle_valid   (B,T,K)
    const float* __restrict__ oshw,    // oracle_should_write (B,T,1)
    const int*   __restrict__ ocid,    // oracle_contract_id (B,T,K)
    float* __restrict__ part)          // [NBLK][6] partials
{
  const int lane = threadIdx.x & 63;
  const int g16  = lane & ~15;         // base lane of this 16-group
  float s0 = 0.f, s1 = 0.f, s2 = 0.f, s3 = 0.f, s4 = 0.f, s5 = 0.f;

  int tid = blockIdx.x * BLOCK + threadIdx.x;
  #pragma unroll
  for (int it = 0; it < ITERS; ++it, tid += STRIDE) {
    const int   my_cid = cid[tid];
    const int   my_oid = ocid[tid];
    const float my_of  = ofire[tid];
    const float my_ov  = ovalid[tid];
    const int   my_oc  = ocan[tid];
    const int   lv     = live[tid];
    const float pf     = trig[tid];
    const float pv     = valp[tid];
    const float l0 = clog[3 * tid + 0];
    const float l1 = clog[3 * tid + 1];
    const float l2 = clog[3 * tid + 2];

    // first-match search over the row's 16 oracle slots
    unsigned mmask = 0u;
    #pragma unroll
    for (int j = 0; j < 16; ++j) {
      int oj = __shfl(my_oid, g16 + j, 64);
      mmask |= (unsigned)(oj == my_cid) << j;
    }
    const bool found = (my_cid != 0) && (mmask != 0u);
    const int  idx   = found ? (__ffs(mmask) - 1) : 0;

    float fire_t = __shfl(my_of, g16 + idx, 64);
    float val_t  = __shfl(my_ov, g16 + idx, 64);
    int   can_t  = __shfl(my_oc, g16 + idx, 64);
    fire_t = found ? fire_t : 0.f;
    val_t  = found ? val_t  : 0.f;
    can_t  = found ? can_t  : 0;

    const float m = lv ? 1.f : 0.f;

    // masked BCE (fire): p in [EPS, 1-EPS] -> inner clips are no-ops
    const float p  = fminf(fmaxf(pf, EPS_F), 1.f - EPS_F);
    const float bf = -(fire_t * logf(p) + (1.f - fire_t) * logf(1.f - p));
    // masked BCE (valid)
    const float q  = fminf(fmaxf(pv, EPS_F), 1.f - EPS_F);
    const float bv = -(val_t * logf(q) + (1.f - val_t) * logf(1.f - q));

    // cancel CE over 3 logits
    const float has = (can_t > 0 && lv) ? 1.f : 0.f;
    int tgt = can_t - 1; tgt = tgt < 0 ? 0 : tgt;
    const float mx  = fmaxf(l0, fmaxf(l1, l2));
    const float lse = mx + logf(expf(l0 - mx) + expf(l1 - mx) + expf(l2 - mx));
    const float lt  = (tgt == 0) ? l0 : ((tgt == 1) ? l1 : l2);

    s0 += bf * m;          // fire bce sum
    s1 += m;               // live count
    s2 += (lse - lt) * has;// cancel ce sum
    s3 += has;             // has count
    s4 += bv * m;          // valid bce sum

    if ((tid & 15) == 0) { // one write-term per row
      const int row = tid >> 4;
      const float x = wscore[row];
      const float y = oshw[row];
      s5 += fmaxf(x, 0.f) - x * y + log1pf(expf(-fabsf(x)));
    }
  }

  // wave reduce (64 lanes), then block reduce via LDS
  float v[6] = {s0, s1, s2, s3, s4, s5};
  #pragma unroll
  for (int off = 32; off > 0; off >>= 1) {
    #pragma unroll
    for (int i = 0; i < 6; ++i) v[i] += __shfl_down(v[i], off, 64);
  }
  __shared__ float red[4][6];
  const int w = threadIdx.x >> 6;
  if (lane == 0) {
    #pragma unroll
    for (int i = 0; i < 6; ++i) red[w][i] = v[i];
  }
  __syncthreads();
  if (threadIdx.x == 0) {
    #pragma unroll
    for (int i = 0; i < 6; ++i)
      part[blockIdx.x * 6 + i] = red[0][i] + red[1][i] + red[2][i] + red[3][i];
  }
}

// Kernel 2: reduce NBLK partials in double, compute the 5 outputs.
__global__ __launch_bounds__(BLOCK) void loss_finalize(
    const float* __restrict__ part, float* __restrict__ out)
{
  double v[6] = {0, 0, 0, 0, 0, 0};
  for (int r = threadIdx.x; r < NBLK; r += BLOCK) {
    #pragma unroll
    for (int i = 0; i < 6; ++i) v[i] += (double)part[r * 6 + i];
  }
  #pragma unroll
  for (int off = 32; off > 0; off >>= 1) {
    #pragma unroll
    for (int i = 0; i < 6; ++i) v[i] += __shfl_down(v[i], off, 64);
  }
  __shared__ double red[4][6];
  const int w = threadIdx.x >> 6, lane = threadIdx.x & 63;
  if (lane == 0) {
    #pragma unroll
    for (int i = 0; i < 6; ++i) red[w][i] = v[i];
  }
  __syncthreads();
  if (threadIdx.x == 0) {
    double a[6];
    #pragma unroll
    for (int i = 0; i < 6; ++i) a[i] = red[0][i] + red[1][i] + red[2][i] + red[3][i];
    const double live_n = a[1] < 1.0 ? 1.0 : a[1];
    const double fire   = a[0] / live_n;                                   // LAM_FIRE   = 1.0
    const double cancel = (a[3] > 0.0) ? a[2] / (a[3] < 1.0 ? 1.0 : a[3])  // LAM_CANCEL = 1.0
                                       : 0.0;
    const double valid  = 0.5 * a[4] / live_n;                             // LAM_VALID  = 0.5
    const double wr     = 0.5 * a[5] / (double)ROWS;                       // LAM_WRITE  = 0.5
    out[0] = (float)fire;
    out[1] = (float)cancel;
    out[2] = (float)valid;
    out[3] = (float)wr;
    out[4] = (float)(fire + cancel + valid + wr);
  }
}

extern "C" void kernel_launch(void* const* d_in, const int* in_sizes, int n_in,
                              void* d_out, int out_size, void* d_ws, size_t ws_size,
                              hipStream_t stream) {
  const float* trig   = (const float*)d_in[0];
  const float* valp   = (const float*)d_in[1];
  const float* clog   = (const float*)d_in[2];
  const float* wscore = (const float*)d_in[3];
  const int*   live   = (const int*)  d_in[4];
  const int*   cid    = (const int*)  d_in[5];
  const float* ofire  = (const float*)d_in[6];
  const int*   ocan   = (const int*)  d_in[7];
  const float* ovalid = (const float*)d_in[8];
  const float* oshw   = (const float*)d_in[9];
  const int*   ocid   = (const int*)  d_in[10];
  float* out  = (float*)d_out;
  float* part = (float*)d_ws;   // NBLK*6 floats = 48 KB, fully overwritten

  loss_main<<<NBLK, BLOCK, 0, stream>>>(trig, valp, clog, wscore, live, cid,
                                        ofire, ocan, ovalid, oshw, ocid, part);
  loss_finalize<<<1, BLOCK, 0, stream>>>(part, out);
}

// Round 2
// 218.132 us; speedup vs baseline: 1.0154x; 1.0154x over previous
//
#include <hip/hip_runtime.h>
#include <math.h>

#define EPS_F 1e-7f

constexpr int Bc = 32, Tc = 8192, Kc = 16;
constexpr int ROWS  = Bc * Tc;        // 262144
constexpr int BLOCK = 256;
constexpr int NBLK  = ROWS / BLOCK;   // 1024 blocks, 1 row per thread

// One thread per (b,t) row. contract ids are in [0,32); the per-slot oracle
// payload is 4 bits (fire|valid<<1|cancel<<2), so the whole row's oracle
// table fits in two u64 nibble-tables + a 32-bit found bitmap, built
// first-match-wins in registers. No cross-lane ops, no LDS in the hot path.
__global__ __launch_bounds__(BLOCK) void loss_main(
    const float* __restrict__ trig,    // trigger_hazard (B,T,K)
    const float* __restrict__ valp,    // validity       (B,T,K)
    const float* __restrict__ clog,    // cancel_logits  (B,T,K,3)
    const float* __restrict__ wscore,  // write_score    (B,T,1)
    const int*   __restrict__ live,    // live_mask      (B,T,K) 0/1
    const int*   __restrict__ cid,     // contract_id    (B,T,K)
    const float* __restrict__ ofire,   // oracle_fire    (B,T,K)
    const int*   __restrict__ ocan,    // oracle_cancel  (B,T,K)
    const float* __restrict__ ovalid,  // oracle_valid   (B,T,K)
    const float* __restrict__ oshw,    // oracle_should_write (B,T,1)
    const int*   __restrict__ ocid,    // oracle_contract_id (B,T,K)
    float* __restrict__ part)          // [NBLK][6] partials
{
  const int row = blockIdx.x * BLOCK + threadIdx.x;

  const int4*   ocid4 = (const int4*)  ocid  + row * 4;
  const int4*   ocan4 = (const int4*)  ocan  + row * 4;
  const float4* ofr4  = (const float4*)ofire + row * 4;
  const float4* ovl4  = (const float4*)ovalid+ row * 4;
  const int4*   cid4  = (const int4*)  cid   + row * 4;
  const int4*   liv4  = (const int4*)  live  + row * 4;
  const float4* trg4  = (const float4*)trig  + row * 4;
  const float4* vlp4  = (const float4*)valp  + row * 4;
  const float4* clg4  = (const float4*)clog  + row * 12;

  // ---- build oracle table (first match wins: skip slot if id already seen)
  unsigned found32 = 0u;
  unsigned long long tblLo = 0ull, tblHi = 0ull;
  #pragma unroll
  for (int ch = 0; ch < 4; ++ch) {
    const int4   oc = ocid4[ch];
    const int4   cc = ocan4[ch];
    const float4 ff = ofr4[ch];
    const float4 vv = ovl4[ch];
    const int ocs[4] = {oc.x, oc.y, oc.z, oc.w};
    const int ccs[4] = {cc.x, cc.y, cc.z, cc.w};
    const float ffs[4] = {ff.x, ff.y, ff.z, ff.w};
    const float vvs[4] = {vv.x, vv.y, vv.z, vv.w};
    #pragma unroll
    for (int j = 0; j < 4; ++j) {
      const unsigned c   = (unsigned)ocs[j] & 31u;
      const unsigned nib = (unsigned)ffs[j] | ((unsigned)vvs[j] << 1) |
                           ((unsigned)ccs[j] << 2);
      const unsigned upd = ((found32 >> c) & 1u) ^ 1u;   // 1 if first sighting
      const unsigned long long val =
          (unsigned long long)(nib * upd) << ((c & 15u) * 4u);
      tblLo |= (c < 16u) ? val : 0ull;
      tblHi |= (c < 16u) ? 0ull : val;
      found32 |= 1u << c;
    }
  }

  // ---- per-slot losses
  float s0 = 0.f, s1 = 0.f, s2 = 0.f, s3 = 0.f, s4 = 0.f;
  #pragma unroll
  for (int ch = 0; ch < 4; ++ch) {
    const int4   cd = cid4[ch];
    const int4   lm = liv4[ch];
    const float4 ph = trg4[ch];
    const float4 pv = vlp4[ch];
    const float4 lA = clg4[ch * 3 + 0];
    const float4 lB = clg4[ch * 3 + 1];
    const float4 lC = clg4[ch * 3 + 2];
    const int   cds[4] = {cd.x, cd.y, cd.z, cd.w};
    const int   lms[4] = {lm.x, lm.y, lm.z, lm.w};
    const float phs[4] = {ph.x, ph.y, ph.z, ph.w};
    const float pvs[4] = {pv.x, pv.y, pv.z, pv.w};
    const float L0[4] = {lA.x, lA.w, lB.z, lC.y};
    const float L1[4] = {lA.y, lB.x, lB.w, lC.z};
    const float L2[4] = {lA.z, lB.y, lC.x, lC.w};
    #pragma unroll
    for (int j = 0; j < 4; ++j) {
      const unsigned c = (unsigned)cds[j];
      const bool fnd = (c != 0u) && ((found32 >> c) & 1u);
      const unsigned long long sel = (c < 16u) ? tblLo : tblHi;
      unsigned nib = (unsigned)(sel >> ((c & 15u) * 4u)) & 15u;
      nib = fnd ? nib : 0u;
      const float fire_t = (float)(nib & 1u);
      const float val_t  = (float)((nib >> 1) & 1u);
      const int   can_t  = (int)(nib >> 2);

      const float m = lms[j] ? 1.f : 0.f;

      // BCE with y in {0,1}: -log(y ? p : 1-p)
      const float p  = fminf(fmaxf(phs[j], EPS_F), 1.f - EPS_F);
      const float bf = -__logf((fire_t != 0.f) ? p : 1.f - p);
      const float q  = fminf(fmaxf(pvs[j], EPS_F), 1.f - EPS_F);
      const float bv = -__logf((val_t != 0.f) ? q : 1.f - q);

      // cancel CE over 3 logits
      const float has = (can_t > 0 && lms[j]) ? 1.f : 0.f;
      const int tgt = (can_t - 1) < 0 ? 0 : (can_t - 1);
      const float l0 = L0[j], l1 = L1[j], l2 = L2[j];
      const float mx  = fmaxf(l0, fmaxf(l1, l2));
      const float lse = mx + __logf(__expf(l0 - mx) + __expf(l1 - mx) +
                                    __expf(l2 - mx));
      const float lt  = (tgt == 0) ? l0 : ((tgt == 1) ? l1 : l2);

      s0 += bf * m;
      s1 += m;
      s2 += (lse - lt) * has;
      s3 += has;
      s4 += bv * m;
    }
  }

  // ---- write term (one per row)
  const float x = wscore[row];
  const float y = oshw[row];
  const float s5 = fmaxf(x, 0.f) - x * y + __logf(1.f + __expf(-fabsf(x)));

  // ---- wave reduce (64 lanes), then block reduce via LDS
  float v[6] = {s0, s1, s2, s3, s4, s5};
  #pragma unroll
  for (int off = 32; off > 0; off >>= 1) {
    #pragma unroll
    for (int i = 0; i < 6; ++i) v[i] += __shfl_down(v[i], off, 64);
  }
  __shared__ float red[4][6];
  const int w = threadIdx.x >> 6, lane = threadIdx.x & 63;
  if (lane == 0) {
    #pragma unroll
    for (int i = 0; i < 6; ++i) red[w][i] = v[i];
  }
  __syncthreads();
  if (threadIdx.x == 0) {
    #pragma unroll
    for (int i = 0; i < 6; ++i)
      part[blockIdx.x * 6 + i] = red[0][i] + red[1][i] + red[2][i] + red[3][i];
  }
}

// Reduce NBLK partials in double, compute the 5 outputs.
__global__ __launch_bounds__(BLOCK) void loss_finalize(
    const float* __restrict__ part, float* __restrict__ out)
{
  double v[6] = {0, 0, 0, 0, 0, 0};
  for (int r = threadIdx.x; r < NBLK; r += BLOCK) {
    #pragma unroll
    for (int i = 0; i < 6; ++i) v[i] += (double)part[r * 6 + i];
  }
  #pragma unroll
  for (int off = 32; off > 0; off >>= 1) {
    #pragma unroll
    for (int i = 0; i < 6; ++i) v[i] += __shfl_down(v[i], off, 64);
  }
  __shared__ double red[4][6];
  const int w = threadIdx.x >> 6, lane = threadIdx.x & 63;
  if (lane == 0) {
    #pragma unroll
    for (int i = 0; i < 6; ++i) red[w][i] = v[i];
  }
  __syncthreads();
  if (threadIdx.x == 0) {
    double a[6];
    #pragma unroll
    for (int i = 0; i < 6; ++i) a[i] = red[0][i] + red[1][i] + red[2][i] + red[3][i];
    const double live_n = a[1] < 1.0 ? 1.0 : a[1];
    const double fire   = a[0] / live_n;                                   // LAM_FIRE   = 1.0
    const double cancel = (a[3] > 0.0) ? a[2] / (a[3] < 1.0 ? 1.0 : a[3])  // LAM_CANCEL = 1.0
                                       : 0.0;
    const double valid  = 0.5 * a[4] / live_n;                             // LAM_VALID  = 0.5
    const double wr     = 0.5 * a[5] / (double)ROWS;                       // LAM_WRITE  = 0.5
    out[0] = (float)fire;
    out[1] = (float)cancel;
    out[2] = (float)valid;
    out[3] = (float)wr;
    out[4] = (float)(fire + cancel + valid + wr);
  }
}

extern "C" void kernel_launch(void* const* d_in, const int* in_sizes, int n_in,
                              void* d_out, int out_size, void* d_ws, size_t ws_size,
                              hipStream_t stream) {
  const float* trig   = (const float*)d_in[0];
  const float* valp   = (const float*)d_in[1];
  const float* clog   = (const float*)d_in[2];
  const float* wscore = (const float*)d_in[3];
  const int*   live   = (const int*)  d_in[4];
  const int*   cid    = (const int*)  d_in[5];
  const float* ofire  = (const float*)d_in[6];
  const int*   ocan   = (const int*)  d_in[7];
  const float* ovalid = (const float*)d_in[8];
  const float* oshw   = (const float*)d_in[9];
  const int*   ocid   = (const int*)  d_in[10];
  float* out  = (float*)d_out;
  float* part = (float*)d_ws;   // NBLK*6 floats = 24 KB, fully overwritten

  loss_main<<<NBLK, BLOCK, 0, stream>>>(trig, valp, clog, wscore, live, cid,
                                        ofire, ocan, ovalid, oshw, ocid, part);
  loss_finalize<<<1, BLOCK, 0, stream>>>(part, out);
}

// Round 3
// 214.206 us; speedup vs baseline: 1.0340x; 1.0183x over previous
//
#include <hip/hip_runtime.h>
#include <math.h>

#define EPS_F 1e-7f

constexpr int Bc = 32, Tc = 8192, Kc = 16;
constexpr int ROWS  = Bc * Tc;           // 262144
constexpr int BLOCK = 256;
constexpr int ROWS_PER_BLK = BLOCK / 4;  // 64 rows per block (4 threads/row)
constexpr int NBLK  = ROWS / ROWS_PER_BLK;  // 4096 blocks

typedef unsigned long long u64;

__device__ __forceinline__ u64 shflx64(u64 v, int m) {
  unsigned lo = __shfl_xor((unsigned)v, m, 64);
  unsigned hi = __shfl_xor((unsigned)(v >> 32), m, 64);
  return ((u64)hi << 32) | lo;
}

// 4 threads per row; thread handles k-slots 4j..4j+3. Oracle table = 4-bit
// nibble per contract id (fire|valid<<1|cancel<<2) in two u64 + a u64
// nibble-mask "found" set (0xF per seen id), built first-match-wins per lane
// then merged across the 4-lane group with lane-order priority (= slot order).
__global__ __launch_bounds__(BLOCK) void loss_main(
    const float* __restrict__ trig,    // trigger_hazard (B,T,K)
    const float* __restrict__ valp,    // validity       (B,T,K)
    const float* __restrict__ clog,    // cancel_logits  (B,T,K,3)
    const float* __restrict__ wscore,  // write_score    (B,T,1)
    const int*   __restrict__ live,    // live_mask      (B,T,K) 0/1
    const int*   __restrict__ cid,     // contract_id    (B,T,K)
    const float* __restrict__ ofire,   // oracle_fire    (B,T,K)
    const int*   __restrict__ ocan,    // oracle_cancel  (B,T,K)
    const float* __restrict__ ovalid,  // oracle_valid   (B,T,K)
    const float* __restrict__ oshw,    // oracle_should_write (B,T,1)
    const int*   __restrict__ ocid,    // oracle_contract_id (B,T,K)
    float* __restrict__ part)          // [NBLK][6] partials
{
  const int t    = blockIdx.x * BLOCK + threadIdx.x;  // global vec4 index
  const int lane = threadIdx.x & 63;

  // ---- issue ALL loads up front (independent; max MLP)
  const int4   oc = ((const int4*)  ocid)[t];
  const int4   cc = ((const int4*)  ocan)[t];
  const float4 ff = ((const float4*)ofire)[t];
  const float4 vv = ((const float4*)ovalid)[t];
  const int4   cd = ((const int4*)  cid)[t];
  const int4   lm = ((const int4*)  live)[t];
  const float4 ph = ((const float4*)trig)[t];
  const float4 pq = ((const float4*)valp)[t];
  const float4 lA = ((const float4*)clog)[t * 3 + 0];
  const float4 lB = ((const float4*)clog)[t * 3 + 1];
  const float4 lC = ((const float4*)clog)[t * 3 + 2];
  float ws_x = 0.f, ws_y = 0.f;
  if (threadIdx.x < ROWS_PER_BLK) {
    const int r2 = blockIdx.x * ROWS_PER_BLK + threadIdx.x;
    ws_x = wscore[r2];
    ws_y = oshw[r2];
  }

  // ---- build my partial oracle table (my 4 slots, in slot order)
  u64 tblLo = 0ull, tblHi = 0ull, fndLo = 0ull, fndHi = 0ull;
  {
    const int   ocs[4] = {oc.x, oc.y, oc.z, oc.w};
    const int   ccs[4] = {cc.x, cc.y, cc.z, cc.w};
    const float ffs[4] = {ff.x, ff.y, ff.z, ff.w};
    const float vvs[4] = {vv.x, vv.y, vv.z, vv.w};
    #pragma unroll
    for (int j = 0; j < 4; ++j) {
      const unsigned c  = (unsigned)ocs[j] & 31u;
      const unsigned sh = (c & 15u) * 4u;
      const bool isLo   = c < 16u;
      const u64 fsel    = isLo ? fndLo : fndHi;
      const bool seen   = ((fsel >> sh) & 1ull) != 0ull;
      const unsigned nib = (unsigned)ffs[j] | ((unsigned)vvs[j] << 1) |
                           ((unsigned)ccs[j] << 2);
      const u64 add  = seen ? 0ull : ((u64)nib << sh);
      const u64 fadd = 0xFull << sh;
      tblLo |= isLo ? add : 0ull;
      tblHi |= isLo ? 0ull : add;
      fndLo |= isLo ? fadd : 0ull;
      fndHi |= isLo ? 0ull : fadd;
    }
  }

  // ---- merge across the 4-lane row group (lower lane = earlier slots wins)
  #pragma unroll
  for (int m = 1; m <= 2; m <<= 1) {
    const u64 pTL = shflx64(tblLo, m);
    const u64 pTH = shflx64(tblHi, m);
    const u64 pFL = shflx64(fndLo, m);
    const u64 pFH = shflx64(fndHi, m);
    const bool iLow = (lane & m) == 0;
    const u64 loTL = iLow ? tblLo : pTL, hiTL = iLow ? pTL : tblLo;
    const u64 loTH = iLow ? tblHi : pTH, hiTH = iLow ? pTH : tblHi;
    const u64 loFL = iLow ? fndLo : pFL, hiFL = iLow ? pFL : fndLo;
    const u64 loFH = iLow ? fndHi : pFH, hiFH = iLow ? pFH : fndHi;
    tblLo = loTL | (hiTL & ~loFL);
    tblHi = loTH | (hiTH & ~loFH);
    fndLo = loFL | hiFL;
    fndHi = loFH | hiFH;
  }

  // ---- per-slot losses for my 4 slots
  float s0 = 0.f, s1 = 0.f, s2 = 0.f, s3 = 0.f, s4 = 0.f;
  {
    const int   cds[4] = {cd.x, cd.y, cd.z, cd.w};
    const int   lms[4] = {lm.x, lm.y, lm.z, lm.w};
    const float phs[4] = {ph.x, ph.y, ph.z, ph.w};
    const float pqs[4] = {pq.x, pq.y, pq.z, pq.w};
    const float L0[4] = {lA.x, lA.w, lB.z, lC.y};
    const float L1[4] = {lA.y, lB.x, lB.w, lC.z};
    const float L2[4] = {lA.z, lB.y, lC.x, lC.w};
    #pragma unroll
    for (int j = 0; j < 4; ++j) {
      const unsigned c  = (unsigned)cds[j] & 31u;
      const unsigned sh = (c & 15u) * 4u;
      const bool isLo   = c < 16u;
      const bool fnd = (c != 0u) &&
                       ((((isLo ? fndLo : fndHi) >> sh) & 1ull) != 0ull);
      unsigned nib = (unsigned)(((isLo ? tblLo : tblHi) >> sh)) & 15u;
      nib = fnd ? nib : 0u;
      const float fire_t = (float)(nib & 1u);
      const float val_t  = (float)((nib >> 1) & 1u);
      const int   can_t  = (int)(nib >> 2);

      const float m = lms[j] ? 1.f : 0.f;

      // BCE with y in {0,1}: -log(y ? p : 1-p)
      const float p  = fminf(fmaxf(phs[j], EPS_F), 1.f - EPS_F);
      const float bf = -__logf((fire_t != 0.f) ? p : 1.f - p);
      const float q  = fminf(fmaxf(pqs[j], EPS_F), 1.f - EPS_F);
      const float bv = -__logf((val_t != 0.f) ? q : 1.f - q);

      // cancel CE over 3 logits
      const float has = (can_t > 0 && lms[j]) ? 1.f : 0.f;
      const int tgt = (can_t - 1) < 0 ? 0 : (can_t - 1);
      const float l0 = L0[j], l1 = L1[j], l2 = L2[j];
      const float mx  = fmaxf(l0, fmaxf(l1, l2));
      const float lse = mx + __logf(__expf(l0 - mx) + __expf(l1 - mx) +
                                    __expf(l2 - mx));
      const float lt  = (tgt == 0) ? l0 : ((tgt == 1) ? l1 : l2);

      s0 += bf * m;
      s1 += m;
      s2 += (lse - lt) * has;
      s3 += has;
      s4 += bv * m;
    }
  }

  // ---- write term (first 64 threads cover the block's 64 rows)
  float s5 = 0.f;
  if (threadIdx.x < ROWS_PER_BLK) {
    s5 = fmaxf(ws_x, 0.f) - ws_x * ws_y + __logf(1.f + __expf(-fabsf(ws_x)));
  }

  // ---- wave reduce (64 lanes), then block reduce via LDS
  float v[6] = {s0, s1, s2, s3, s4, s5};
  #pragma unroll
  for (int off = 32; off > 0; off >>= 1) {
    #pragma unroll
    for (int i = 0; i < 6; ++i) v[i] += __shfl_down(v[i], off, 64);
  }
  __shared__ float red[4][6];
  const int w = threadIdx.x >> 6;
  if (lane == 0) {
    #pragma unroll
    for (int i = 0; i < 6; ++i) red[w][i] = v[i];
  }
  __syncthreads();
  if (threadIdx.x == 0) {
    #pragma unroll
    for (int i = 0; i < 6; ++i)
      part[blockIdx.x * 6 + i] = red[0][i] + red[1][i] + red[2][i] + red[3][i];
  }
}

// Reduce NBLK partials in double, compute the 5 outputs.
__global__ __launch_bounds__(BLOCK) void loss_finalize(
    const float* __restrict__ part, float* __restrict__ out)
{
  double v[6] = {0, 0, 0, 0, 0, 0};
  for (int r = threadIdx.x; r < NBLK; r += BLOCK) {
    #pragma unroll
    for (int i = 0; i < 6; ++i) v[i] += (double)part[r * 6 + i];
  }
  #pragma unroll
  for (int off = 32; off > 0; off >>= 1) {
    #pragma unroll
    for (int i = 0; i < 6; ++i) v[i] += __shfl_down(v[i], off, 64);
  }
  __shared__ double red[4][6];
  const int w = threadIdx.x >> 6, lane = threadIdx.x & 63;
  if (lane == 0) {
    #pragma unroll
    for (int i = 0; i < 6; ++i) red[w][i] = v[i];
  }
  __syncthreads();
  if (threadIdx.x == 0) {
    double a[6];
    #pragma unroll
    for (int i = 0; i < 6; ++i) a[i] = red[0][i] + red[1][i] + red[2][i] + red[3][i];
    const double live_n = a[1] < 1.0 ? 1.0 : a[1];
    const double fire   = a[0] / live_n;                                   // LAM_FIRE   = 1.0
    const double cancel = (a[3] > 0.0) ? a[2] / (a[3] < 1.0 ? 1.0 : a[3])  // LAM_CANCEL = 1.0
                                       : 0.0;
    const double valid  = 0.5 * a[4] / live_n;                             // LAM_VALID  = 0.5
    const double wr     = 0.5 * a[5] / (double)ROWS;                       // LAM_WRITE  = 0.5
    out[0] = (float)fire;
    out[1] = (float)cancel;
    out[2] = (float)valid;
    out[3] = (float)wr;
    out[4] = (float)(fire + cancel + valid + wr);
  }
}

extern "C" void kernel_launch(void* const* d_in, const int* in_sizes, int n_in,
                              void* d_out, int out_size, void* d_ws, size_t ws_size,
                              hipStream_t stream) {
  const float* trig   = (const float*)d_in[0];
  const float* valp   = (const float*)d_in[1];
  const float* clog   = (const float*)d_in[2];
  const float* wscore = (const float*)d_in[3];
  const int*   live   = (const int*)  d_in[4];
  const int*   cid    = (const int*)  d_in[5];
  const float* ofire  = (const float*)d_in[6];
  const int*   ocan   = (const int*)  d_in[7];
  const float* ovalid = (const float*)d_in[8];
  const float* oshw   = (const float*)d_in[9];
  const int*   ocid   = (const int*)  d_in[10];
  float* out  = (float*)d_out;
  float* part = (float*)d_ws;   // NBLK*6 floats = 96 KB, fully overwritten

  loss_main<<<NBLK, BLOCK, 0, stream>>>(trig, valp, clog, wscore, live, cid,
                                        ofire, ocan, ovalid, oshw, ocid, part);
  loss_finalize<<<1, BLOCK, 0, stream>>>(part, out);
}

// Round 4
// 213.114 us; speedup vs baseline: 1.0393x; 1.0051x over previous
//
#include <hip/hip_runtime.h>
#include <math.h>

#define EPS_F 1e-7f

constexpr int Bc = 32, Tc = 8192, Kc = 16;
constexpr int ROWS   = Bc * Tc;          // 262144
constexpr int BLOCK  = 256;
constexpr int NBLK   = 1024;             // 4 blocks/CU
constexpr int ITEMS  = 4;                // vec4-items per thread
constexpr int STRIDE = NBLK * BLOCK;     // 262144 vec4 items per sweep
// total vec4 items = ROWS*4 = 1048576 = ITEMS*STRIDE  ✓

typedef unsigned long long u64;

__device__ __forceinline__ u64 shflx64(u64 v, int m) {
  unsigned lo = __shfl_xor((unsigned)v, m, 64);
  unsigned hi = __shfl_xor((unsigned)(v >> 32), m, 64);
  return ((u64)hi << 32) | lo;
}

struct Item {
  int4   oc, cc, cd, lm;
  float4 ff, vv, ph, pq, lA, lB, lC;
  float  wx, wy;
};

// 4 threads per row (thread = one vec4 of k-slots). Software-pipelined
// grid-stride loop: issue item i+1's 11 vec4 loads before computing item i,
// keeping ~11KB per wave in flight continuously. Oracle table = 4-bit nibble
// per contract id in two u64 + u64 nibble "found" mask, built per-lane then
// merged across the 4-lane row group (lower lane = earlier slot wins).
__global__ __launch_bounds__(BLOCK, 2) void loss_main(
    const float* __restrict__ trig,
    const float* __restrict__ valp,
    const float* __restrict__ clog,
    const float* __restrict__ wscore,
    const int*   __restrict__ live,
    const int*   __restrict__ cid,
    const float* __restrict__ ofire,
    const int*   __restrict__ ocan,
    const float* __restrict__ ovalid,
    const float* __restrict__ oshw,
    const int*   __restrict__ ocid,
    float* __restrict__ part)            // [NBLK][6]
{
  const int  lane      = threadIdx.x & 63;
  const bool isRowLead = (threadIdx.x & 3) == 0;   // t%4 invariant across items

  const int4*   ocid4 = (const int4*)  ocid;
  const int4*   ocan4 = (const int4*)  ocan;
  const float4* ofr4  = (const float4*)ofire;
  const float4* ovl4  = (const float4*)ovalid;
  const int4*   cid4  = (const int4*)  cid;
  const int4*   liv4  = (const int4*)  live;
  const float4* trg4  = (const float4*)trig;
  const float4* vlp4  = (const float4*)valp;
  const float4* clg4  = (const float4*)clog;

  float s0 = 0.f, s1 = 0.f, s2 = 0.f, s3 = 0.f, s4 = 0.f, s5 = 0.f;

  auto load_item = [&](int t, Item& it) {
    it.oc = ocid4[t];
    it.cc = ocan4[t];
    it.ff = ofr4[t];
    it.vv = ovl4[t];
    it.cd = cid4[t];
    it.lm = liv4[t];
    it.ph = trg4[t];
    it.pq = vlp4[t];
    it.lA = clg4[t * 3 + 0];
    it.lB = clg4[t * 3 + 1];
    it.lC = clg4[t * 3 + 2];
    it.wx = 0.f; it.wy = 0.f;
    if (isRowLead) { it.wx = wscore[t >> 2]; it.wy = oshw[t >> 2]; }
  };

  auto compute = [&](const Item& it) {
    // ---- per-lane partial oracle table (my 4 slots, slot order)
    u64 tblLo = 0ull, tblHi = 0ull, fndLo = 0ull, fndHi = 0ull;
    {
      const int   ocs[4] = {it.oc.x, it.oc.y, it.oc.z, it.oc.w};
      const int   ccs[4] = {it.cc.x, it.cc.y, it.cc.z, it.cc.w};
      const float ffs[4] = {it.ff.x, it.ff.y, it.ff.z, it.ff.w};
      const float vvs[4] = {it.vv.x, it.vv.y, it.vv.z, it.vv.w};
      #pragma unroll
      for (int j = 0; j < 4; ++j) {
        const unsigned c  = (unsigned)ocs[j] & 31u;
        const unsigned sh = (c & 15u) * 4u;
        const bool isLo   = c < 16u;
        const bool seen   = (((isLo ? fndLo : fndHi) >> sh) & 1ull) != 0ull;
        const unsigned nib = (unsigned)ffs[j] | ((unsigned)vvs[j] << 1) |
                             ((unsigned)ccs[j] << 2);
        const u64 add  = seen ? 0ull : ((u64)nib << sh);
        const u64 fadd = 0xFull << sh;
        tblLo |= isLo ? add : 0ull;
        tblHi |= isLo ? 0ull : add;
        fndLo |= isLo ? fadd : 0ull;
        fndHi |= isLo ? 0ull : fadd;
      }
    }
    // ---- merge across 4-lane row group (lower lane wins)
    #pragma unroll
    for (int m = 1; m <= 2; m <<= 1) {
      const u64 pTL = shflx64(tblLo, m);
      const u64 pTH = shflx64(tblHi, m);
      const u64 pFL = shflx64(fndLo, m);
      const u64 pFH = shflx64(fndHi, m);
      const bool iLow = (lane & m) == 0;
      const u64 loTL = iLow ? tblLo : pTL, hiTL = iLow ? pTL : tblLo;
      const u64 loTH = iLow ? tblHi : pTH, hiTH = iLow ? pTH : tblHi;
      const u64 loFL = iLow ? fndLo : pFL, hiFL = iLow ? pFL : fndLo;
      const u64 loFH = iLow ? fndHi : pFH, hiFH = iLow ? pFH : fndHi;
      tblLo = loTL | (hiTL & ~loFL);
      tblHi = loTH | (hiTH & ~loFH);
      fndLo = loFL | hiFL;
      fndHi = loFH | hiFH;
    }
    // ---- losses for my 4 slots
    {
      const int   cds[4] = {it.cd.x, it.cd.y, it.cd.z, it.cd.w};
      const int   lms[4] = {it.lm.x, it.lm.y, it.lm.z, it.lm.w};
      const float phs[4] = {it.ph.x, it.ph.y, it.ph.z, it.ph.w};
      const float pqs[4] = {it.pq.x, it.pq.y, it.pq.z, it.pq.w};
      const float L0[4] = {it.lA.x, it.lA.w, it.lB.z, it.lC.y};
      const float L1[4] = {it.lA.y, it.lB.x, it.lB.w, it.lC.z};
      const float L2[4] = {it.lA.z, it.lB.y, it.lC.x, it.lC.w};
      #pragma unroll
      for (int j = 0; j < 4; ++j) {
        const unsigned c  = (unsigned)cds[j] & 31u;
        const unsigned sh = (c & 15u) * 4u;
        const bool isLo   = c < 16u;
        const bool fnd = (c != 0u) &&
                         ((((isLo ? fndLo : fndHi) >> sh) & 1ull) != 0ull);
        unsigned nib = (unsigned)(((isLo ? tblLo : tblHi) >> sh)) & 15u;
        nib = fnd ? nib : 0u;
        const float fire_t = (float)(nib & 1u);
        const float val_t  = (float)((nib >> 1) & 1u);
        const int   can_t  = (int)(nib >> 2);

        const float m = lms[j] ? 1.f : 0.f;

        const float p  = fminf(fmaxf(phs[j], EPS_F), 1.f - EPS_F);
        const float bf = -__logf((fire_t != 0.f) ? p : 1.f - p);
        const float q  = fminf(fmaxf(pqs[j], EPS_F), 1.f - EPS_F);
        const float bv = -__logf((val_t != 0.f) ? q : 1.f - q);

        const float has = (can_t > 0 && lms[j]) ? 1.f : 0.f;
        const int tgt = (can_t - 1) < 0 ? 0 : (can_t - 1);
        const float l0 = L0[j], l1 = L1[j], l2 = L2[j];
        const float mx  = fmaxf(l0, fmaxf(l1, l2));
        const float lse = mx + __logf(__expf(l0 - mx) + __expf(l1 - mx) +
                                      __expf(l2 - mx));
        const float lt  = (tgt == 0) ? l0 : ((tgt == 1) ? l1 : l2);

        s0 += bf * m;
        s1 += m;
        s2 += (lse - lt) * has;
        s3 += has;
        s4 += bv * m;
      }
    }
    // ---- write term (one lane per row)
    if (isRowLead) {
      const float x = it.wx, y = it.wy;
      s5 += fmaxf(x, 0.f) - x * y + __logf(1.f + __expf(-fabsf(x)));
    }
  };

  // ---- software pipeline over ITEMS grid-stride chunks
  int t = blockIdx.x * BLOCK + threadIdx.x;
  Item buf[2];
  load_item(t, buf[0]);
  #pragma unroll
  for (int i = 0; i < ITEMS; ++i) {
    if (i + 1 < ITEMS) load_item(t + STRIDE, buf[(i + 1) & 1]);
    compute(buf[i & 1]);
    t += STRIDE;
  }

  // ---- wave reduce, then block reduce via LDS
  float v[6] = {s0, s1, s2, s3, s4, s5};
  #pragma unroll
  for (int off = 32; off > 0; off >>= 1) {
    #pragma unroll
    for (int i = 0; i < 6; ++i) v[i] += __shfl_down(v[i], off, 64);
  }
  __shared__ float red[4][6];
  const int w = threadIdx.x >> 6;
  if (lane == 0) {
    #pragma unroll
    for (int i = 0; i < 6; ++i) red[w][i] = v[i];
  }
  __syncthreads();
  if (threadIdx.x == 0) {
    #pragma unroll
    for (int i = 0; i < 6; ++i)
      part[blockIdx.x * 6 + i] = red[0][i] + red[1][i] + red[2][i] + red[3][i];
  }
}

// Reduce NBLK partials in double, compute the 5 outputs.
__global__ __launch_bounds__(BLOCK) void loss_finalize(
    const float* __restrict__ part, float* __restrict__ out)
{
  double v[6] = {0, 0, 0, 0, 0, 0};
  for (int r = threadIdx.x; r < NBLK; r += BLOCK) {
    #pragma unroll
    for (int i = 0; i < 6; ++i) v[i] += (double)part[r * 6 + i];
  }
  #pragma unroll
  for (int off = 32; off > 0; off >>= 1) {
    #pragma unroll
    for (int i = 0; i < 6; ++i) v[i] += __shfl_down(v[i], off, 64);
  }
  __shared__ double red[4][6];
  const int w = threadIdx.x >> 6, lane = threadIdx.x & 63;
  if (lane == 0) {
    #pragma unroll
    for (int i = 0; i < 6; ++i) red[w][i] = v[i];
  }
  __syncthreads();
  if (threadIdx.x == 0) {
    double a[6];
    #pragma unroll
    for (int i = 0; i < 6; ++i) a[i] = red[0][i] + red[1][i] + red[2][i] + red[3][i];
    const double live_n = a[1] < 1.0 ? 1.0 : a[1];
    const double fire   = a[0] / live_n;                                   // LAM_FIRE   = 1.0
    const double cancel = (a[3] > 0.0) ? a[2] / (a[3] < 1.0 ? 1.0 : a[3])  // LAM_CANCEL = 1.0
                                       : 0.0;
    const double valid  = 0.5 * a[4] / live_n;                             // LAM_VALID  = 0.5
    const double wr     = 0.5 * a[5] / (double)ROWS;                       // LAM_WRITE  = 0.5
    out[0] = (float)fire;
    out[1] = (float)cancel;
    out[2] = (float)valid;
    out[3] = (float)wr;
    out[4] = (float)(fire + cancel + valid + wr);
  }
}

extern "C" void kernel_launch(void* const* d_in, const int* in_sizes, int n_in,
                              void* d_out, int out_size, void* d_ws, size_t ws_size,
                              hipStream_t stream) {
  const float* trig   = (const float*)d_in[0];
  const float* valp   = (const float*)d_in[1];
  const float* clog   = (const float*)d_in[2];
  const float* wscore = (const float*)d_in[3];
  const int*   live   = (const int*)  d_in[4];
  const int*   cid    = (const int*)  d_in[5];
  const float* ofire  = (const float*)d_in[6];
  const int*   ocan   = (const int*)  d_in[7];
  const float* ovalid = (const float*)d_in[8];
  const float* oshw   = (const float*)d_in[9];
  const int*   ocid   = (const int*)  d_in[10];
  float* out  = (float*)d_out;
  float* part = (float*)d_ws;   // NBLK*6 floats = 24 KB, fully overwritten

  loss_main<<<NBLK, BLOCK, 0, stream>>>(trig, valp, clog, wscore, live, cid,
                                        ofire, ocan, ovalid, oshw, ocid, part);
  loss_finalize<<<1, BLOCK, 0, stream>>>(part, out);
}

// Round 5
// 209.639 us; speedup vs baseline: 1.0565x; 1.0166x over previous
//
#include <hip/hip_runtime.h>
#include <math.h>

#define EPS_F 1e-7f

constexpr int Bc = 32, Tc = 8192, Kc = 16;
constexpr int ROWS   = Bc * Tc;          // 262144
constexpr int BLOCK  = 256;
constexpr int NBLK   = 2048;             // 8 blocks/CU demand
constexpr int ITEMS  = 2;                // vec4-items per thread
constexpr int STRIDE = NBLK * BLOCK;     // 524288 vec4 items per sweep
// total vec4 items = ROWS*4 = 1048576 = ITEMS*STRIDE  ✓

typedef unsigned long long u64;

__device__ __forceinline__ u64 shflx64(u64 v, int m) {
  unsigned lo = __shfl_xor((unsigned)v, m, 64);
  unsigned hi = __shfl_xor((unsigned)(v >> 32), m, 64);
  return ((u64)hi << 32) | lo;
}

struct Item {
  int4   oc, cc, cd, lm;
  float4 ff, vv, ph, pq, lA, lB, lC;
  float  wx, wy;
};

// 4 threads per row (thread = one vec4 of k-slots). Software-pipelined
// grid-stride loop: issue item i+1's 11 vec4 loads before computing item i
// (double-buffer Item struct forces ~11KB/wave of loads to stay in flight),
// while 2048 blocks give 8 blocks/CU of TLP (R3 lesson) -- R4 had the MLP
// but only 1024 blocks; R3 had the TLP but the compiler sank loads to 32
// VGPR. Oracle table = 4-bit nibble per contract id in two u64 + u64 nibble
// "found" mask, built per-lane then merged across the 4-lane row group
// (lower lane = earlier slot wins).
__global__ __launch_bounds__(BLOCK, 2) void loss_main(
    const float* __restrict__ trig,
    const float* __restrict__ valp,
    const float* __restrict__ clog,
    const float* __restrict__ wscore,
    const int*   __restrict__ live,
    const int*   __restrict__ cid,
    const float* __restrict__ ofire,
    const int*   __restrict__ ocan,
    const float* __restrict__ ovalid,
    const float* __restrict__ oshw,
    const int*   __restrict__ ocid,
    float* __restrict__ part)            // [NBLK][6]
{
  const int  lane      = threadIdx.x & 63;
  const bool isRowLead = (threadIdx.x & 3) == 0;   // t%4 invariant across items

  const int4*   ocid4 = (const int4*)  ocid;
  const int4*   ocan4 = (const int4*)  ocan;
  const float4* ofr4  = (const float4*)ofire;
  const float4* ovl4  = (const float4*)ovalid;
  const int4*   cid4  = (const int4*)  cid;
  const int4*   liv4  = (const int4*)  live;
  const float4* trg4  = (const float4*)trig;
  const float4* vlp4  = (const float4*)valp;
  const float4* clg4  = (const float4*)clog;

  float s0 = 0.f, s1 = 0.f, s2 = 0.f, s3 = 0.f, s4 = 0.f, s5 = 0.f;

  auto load_item = [&](int t, Item& it) {
    it.oc = ocid4[t];
    it.cc = ocan4[t];
    it.ff = ofr4[t];
    it.vv = ovl4[t];
    it.cd = cid4[t];
    it.lm = liv4[t];
    it.ph = trg4[t];
    it.pq = vlp4[t];
    it.lA = clg4[t * 3 + 0];
    it.lB = clg4[t * 3 + 1];
    it.lC = clg4[t * 3 + 2];
    it.wx = 0.f; it.wy = 0.f;
    if (isRowLead) { it.wx = wscore[t >> 2]; it.wy = oshw[t >> 2]; }
  };

  auto compute = [&](const Item& it) {
    // ---- per-lane partial oracle table (my 4 slots, slot order)
    u64 tblLo = 0ull, tblHi = 0ull, fndLo = 0ull, fndHi = 0ull;
    {
      const int   ocs[4] = {it.oc.x, it.oc.y, it.oc.z, it.oc.w};
      const int   ccs[4] = {it.cc.x, it.cc.y, it.cc.z, it.cc.w};
      const float ffs[4] = {it.ff.x, it.ff.y, it.ff.z, it.ff.w};
      const float vvs[4] = {it.vv.x, it.vv.y, it.vv.z, it.vv.w};
      #pragma unroll
      for (int j = 0; j < 4; ++j) {
        const unsigned c  = (unsigned)ocs[j] & 31u;
        const unsigned sh = (c & 15u) * 4u;
        const bool isLo   = c < 16u;
        const bool seen   = (((isLo ? fndLo : fndHi) >> sh) & 1ull) != 0ull;
        const unsigned nib = (unsigned)ffs[j] | ((unsigned)vvs[j] << 1) |
                             ((unsigned)ccs[j] << 2);
        const u64 add  = seen ? 0ull : ((u64)nib << sh);
        const u64 fadd = 0xFull << sh;
        tblLo |= isLo ? add : 0ull;
        tblHi |= isLo ? 0ull : add;
        fndLo |= isLo ? fadd : 0ull;
        fndHi |= isLo ? 0ull : fadd;
      }
    }
    // ---- merge across 4-lane row group (lower lane wins)
    #pragma unroll
    for (int m = 1; m <= 2; m <<= 1) {
      const u64 pTL = shflx64(tblLo, m);
      const u64 pTH = shflx64(tblHi, m);
      const u64 pFL = shflx64(fndLo, m);
      const u64 pFH = shflx64(fndHi, m);
      const bool iLow = (lane & m) == 0;
      const u64 loTL = iLow ? tblLo : pTL, hiTL = iLow ? pTL : tblLo;
      const u64 loTH = iLow ? tblHi : pTH, hiTH = iLow ? pTH : tblHi;
      const u64 loFL = iLow ? fndLo : pFL, hiFL = iLow ? pFL : fndLo;
      const u64 loFH = iLow ? fndHi : pFH, hiFH = iLow ? pFH : fndHi;
      tblLo = loTL | (hiTL & ~loFL);
      tblHi = loTH | (hiTH & ~loFH);
      fndLo = loFL | hiFL;
      fndHi = loFH | hiFH;
    }
    // ---- losses for my 4 slots
    {
      const int   cds[4] = {it.cd.x, it.cd.y, it.cd.z, it.cd.w};
      const int   lms[4] = {it.lm.x, it.lm.y, it.lm.z, it.lm.w};
      const float phs[4] = {it.ph.x, it.ph.y, it.ph.z, it.ph.w};
      const float pqs[4] = {it.pq.x, it.pq.y, it.pq.z, it.pq.w};
      const float L0[4] = {it.lA.x, it.lA.w, it.lB.z, it.lC.y};
      const float L1[4] = {it.lA.y, it.lB.x, it.lB.w, it.lC.z};
      const float L2[4] = {it.lA.z, it.lB.y, it.lC.x, it.lC.w};
      #pragma unroll
      for (int j = 0; j < 4; ++j) {
        const unsigned c  = (unsigned)cds[j] & 31u;
        const unsigned sh = (c & 15u) * 4u;
        const bool isLo   = c < 16u;
        const bool fnd = (c != 0u) &&
                         ((((isLo ? fndLo : fndHi) >> sh) & 1ull) != 0ull);
        unsigned nib = (unsigned)(((isLo ? tblLo : tblHi) >> sh)) & 15u;
        nib = fnd ? nib : 0u;
        const float fire_t = (float)(nib & 1u);
        const float val_t  = (float)((nib >> 1) & 1u);
        const int   can_t  = (int)(nib >> 2);

        const float m = lms[j] ? 1.f : 0.f;

        const float p  = fminf(fmaxf(phs[j], EPS_F), 1.f - EPS_F);
        const float bf = -__logf((fire_t != 0.f) ? p : 1.f - p);
        const float q  = fminf(fmaxf(pqs[j], EPS_F), 1.f - EPS_F);
        const float bv = -__logf((val_t != 0.f) ? q : 1.f - q);

        const float has = (can_t > 0 && lms[j]) ? 1.f : 0.f;
        const int tgt = (can_t - 1) < 0 ? 0 : (can_t - 1);
        const float l0 = L0[j], l1 = L1[j], l2 = L2[j];
        const float mx  = fmaxf(l0, fmaxf(l1, l2));
        const float lse = mx + __logf(__expf(l0 - mx) + __expf(l1 - mx) +
                                      __expf(l2 - mx));
        const float lt  = (tgt == 0) ? l0 : ((tgt == 1) ? l1 : l2);

        s0 += bf * m;
        s1 += m;
        s2 += (lse - lt) * has;
        s3 += has;
        s4 += bv * m;
      }
    }
    // ---- write term (one lane per row)
    if (isRowLead) {
      const float x = it.wx, y = it.wy;
      s5 += fmaxf(x, 0.f) - x * y + __logf(1.f + __expf(-fabsf(x)));
    }
  };

  // ---- software pipeline over ITEMS grid-stride chunks
  int t = blockIdx.x * BLOCK + threadIdx.x;
  Item buf[2];
  load_item(t, buf[0]);
  #pragma unroll
  for (int i = 0; i < ITEMS; ++i) {
    if (i + 1 < ITEMS) load_item(t + STRIDE, buf[(i + 1) & 1]);
    compute(buf[i & 1]);
    t += STRIDE;
  }

  // ---- wave reduce, then block reduce via LDS
  float v[6] = {s0, s1, s2, s3, s4, s5};
  #pragma unroll
  for (int off = 32; off > 0; off >>= 1) {
    #pragma unroll
    for (int i = 0; i < 6; ++i) v[i] += __shfl_down(v[i], off, 64);
  }
  __shared__ float red[4][6];
  const int w = threadIdx.x >> 6;
  if (lane == 0) {
    #pragma unroll
    for (int i = 0; i < 6; ++i) red[w][i] = v[i];
  }
  __syncthreads();
  if (threadIdx.x == 0) {
    #pragma unroll
    for (int i = 0; i < 6; ++i)
      part[blockIdx.x * 6 + i] = red[0][i] + red[1][i] + red[2][i] + red[3][i];
  }
}

// Reduce NBLK partials in double, compute the 5 outputs.
__global__ __launch_bounds__(BLOCK) void loss_finalize(
    const float* __restrict__ part, float* __restrict__ out)
{
  double v[6] = {0, 0, 0, 0, 0, 0};
  for (int r = threadIdx.x; r < NBLK; r += BLOCK) {
    #pragma unroll
    for (int i = 0; i < 6; ++i) v[i] += (double)part[r * 6 + i];
  }
  #pragma unroll
  for (int off = 32; off > 0; off >>= 1) {
    #pragma unroll
    for (int i = 0; i < 6; ++i) v[i] += __shfl_down(v[i], off, 64);
  }
  __shared__ double red[4][6];
  const int w = threadIdx.x >> 6, lane = threadIdx.x & 63;
  if (lane == 0) {
    #pragma unroll
    for (int i = 0; i < 6; ++i) red[w][i] = v[i];
  }
  __syncthreads();
  if (threadIdx.x == 0) {
    double a[6];
    #pragma unroll
    for (int i = 0; i < 6; ++i) a[i] = red[0][i] + red[1][i] + red[2][i] + red[3][i];
    const double live_n = a[1] < 1.0 ? 1.0 : a[1];
    const double fire   = a[0] / live_n;                                   // LAM_FIRE   = 1.0
    const double cancel = (a[3] > 0.0) ? a[2] / (a[3] < 1.0 ? 1.0 : a[3])  // LAM_CANCEL = 1.0
                                       : 0.0;
    const double valid  = 0.5 * a[4] / live_n;                             // LAM_VALID  = 0.5
    const double wr     = 0.5 * a[5] / (double)ROWS;                       // LAM_WRITE  = 0.5
    out[0] = (float)fire;
    out[1] = (float)cancel;
    out[2] = (float)valid;
    out[3] = (float)wr;
    out[4] = (float)(fire + cancel + valid + wr);
  }
}

extern "C" void kernel_launch(void* const* d_in, const int* in_sizes, int n_in,
                              void* d_out, int out_size, void* d_ws, size_t ws_size,
                              hipStream_t stream) {
  const float* trig   = (const float*)d_in[0];
  const float* valp   = (const float*)d_in[1];
  const float* clog   = (const float*)d_in[2];
  const float* wscore = (const float*)d_in[3];
  const int*   live   = (const int*)  d_in[4];
  const int*   cid    = (const int*)  d_in[5];
  const float* ofire  = (const float*)d_in[6];
  const int*   ocan   = (const int*)  d_in[7];
  const float* ovalid = (const float*)d_in[8];
  const float* oshw   = (const float*)d_in[9];
  const int*   ocid   = (const int*)  d_in[10];
  float* out  = (float*)d_out;
  float* part = (float*)d_ws;   // NBLK*6 floats = 48 KB, fully overwritten

  loss_main<<<NBLK, BLOCK, 0, stream>>>(trig, valp, clog, wscore, live, cid,
                                        ofire, ocan, ovalid, oshw, ocid, part);
  loss_finalize<<<1, BLOCK, 0, stream>>>(part, out);
}